// Round 1
// baseline (1126.023 us; speedup 1.0000x reference)
//
#include <hip/hip_runtime.h>
#include <math.h>

#define NROWS 8192
#define DIN   60
#define DZ    16
#define NC    10

#define LOG2E 1.4426950408889634f

// K2 tiling
#define RB  256               // rows per block (1 per thread)
#define CJ  256               // j-range per block (chunk)
#define BJ  64                // j staged per LDS tile
#define NRB (NROWS / RB)      // 32 row blocks
#define NCH (NROWS / CJ)      // 32 j chunks

// ---------------------------------------------------------------------------
// K1: z = fc2(fc1(x)); store z' = z * sqrt(2*temp*log2e) and
//     b_i = log2e*(temp*||z||^2 - theta/2)
// ---------------------------------------------------------------------------
__global__ __launch_bounds__(256) void k1_embed(
    const float* __restrict__ x,
    const float* __restrict__ w1, const float* __restrict__ b1,
    const float* __restrict__ w2, const float* __restrict__ b2,
    const float* __restrict__ temp_p, const float* __restrict__ theta_p,
    float* __restrict__ zp, float* __restrict__ bb)
{
    int i = blockIdx.x * 256 + threadIdx.x;

    float xr[DIN];
    const float4* xp = reinterpret_cast<const float4*>(x + i * DIN); // 240B row stride -> 16B aligned
    #pragma unroll
    for (int c = 0; c < 15; ++c) {
        float4 v = xp[c];
        xr[c*4+0] = v.x; xr[c*4+1] = v.y; xr[c*4+2] = v.z; xr[c*4+3] = v.w;
    }

    float n1[32];
    #pragma unroll
    for (int o = 0; o < 32; ++o) {
        float acc = b1[o];
        #pragma unroll
        for (int k = 0; k < DIN; ++k) acc = fmaf(w1[o*DIN+k], xr[k], acc);
        n1[o] = acc;
    }

    float z[DZ];
    float sq = 0.0f;
    #pragma unroll
    for (int u = 0; u < DZ; ++u) {
        float acc = b2[u];
        #pragma unroll
        for (int o = 0; o < 32; ++o) acc = fmaf(w2[u*32+o], n1[o], acc);
        z[u] = acc;
        sq = fmaf(acc, acc, sq);
    }

    float temp  = *temp_p;
    float theta = *theta_p;
    float s = sqrtf(2.0f * temp * LOG2E);
    #pragma unroll
    for (int u = 0; u < DZ; ++u) zp[i*DZ + u] = z[u] * s;
    bb[i] = LOG2E * fmaf(temp, sq, -0.5f * theta);
}

// ---------------------------------------------------------------------------
// K2: fused pairwise sigmoid + aggregation.
//   thread owns row i; block handles j in [ch*CJ, ch*CJ+CJ), staged in BJ tiles.
//   P_ij = 1/(1+exp2(max(b_i + b_j - z'_i.z'_j, -theta*log2e)))
//   partial (sum_j P_ij * x_j , sum_j P_ij) atomically added to hacc[i][0..60]
// ---------------------------------------------------------------------------
__global__ __launch_bounds__(256) void k2_pair(
    const float* __restrict__ x,
    const float* __restrict__ zp, const float* __restrict__ bb,
    const float* __restrict__ theta_p,
    float* __restrict__ hacc)
{
    __shared__ float xt[BJ][64];   // 60 used, 64 stride for aligned float4 writes
    __shared__ float zt[BJ][DZ];
    __shared__ float bt[BJ];

    const int tid = threadIdx.x;
    const int rb  = blockIdx.x & (NRB - 1);
    const int ch  = blockIdx.x >> 5;          // NRB == 32
    const int i   = rb * RB + tid;
    const int j0  = ch * CJ;

    float zi[DZ];
    const float4* zpi = reinterpret_cast<const float4*>(zp + i * DZ);
    #pragma unroll
    for (int c = 0; c < 4; ++c) {
        float4 v = zpi[c];
        zi[c*4+0] = v.x; zi[c*4+1] = v.y; zi[c*4+2] = v.z; zi[c*4+3] = v.w;
    }
    const float bi = bb[i];
    const float nclamp = -(*theta_p) * LOG2E;

    float acc[DIN];
    #pragma unroll
    for (int k = 0; k < DIN; ++k) acc[k] = 0.0f;
    float rs = 0.0f;

    for (int t = 0; t < CJ / BJ; ++t) {
        const int jb = j0 + t * BJ;
        // ---- stage x tile (BJ*60 floats, contiguous in global) ----
        const float4* xsrc = reinterpret_cast<const float4*>(x + (size_t)jb * DIN);
        for (int idx = tid; idx < BJ * 15; idx += 256) {
            float4 v = xsrc[idx];
            int r = idx / 15, c = idx % 15;
            *reinterpret_cast<float4*>(&xt[r][c*4]) = v;
        }
        // ---- stage z' tile ----
        {
            const float4* zsrc = reinterpret_cast<const float4*>(zp + (size_t)jb * DZ);
            float4 v = zsrc[tid];                       // BJ*4 == 256 threads exactly
            *reinterpret_cast<float4*>(&zt[tid >> 2][(tid & 3) * 4]) = v;
        }
        if (tid < BJ) bt[tid] = bb[jb + tid];
        __syncthreads();

        for (int j = 0; j < BJ; ++j) {
            float4 q0 = *reinterpret_cast<const float4*>(&zt[j][0]);
            float4 q1 = *reinterpret_cast<const float4*>(&zt[j][4]);
            float4 q2 = *reinterpret_cast<const float4*>(&zt[j][8]);
            float4 q3 = *reinterpret_cast<const float4*>(&zt[j][12]);
            float n0 = zi[0]*q0.x, n1 = zi[1]*q0.y, n2 = zi[2]*q0.z, n3 = zi[3]*q0.w;
            n0 = fmaf(zi[4],  q1.x, n0); n1 = fmaf(zi[5],  q1.y, n1);
            n2 = fmaf(zi[6],  q1.z, n2); n3 = fmaf(zi[7],  q1.w, n3);
            n0 = fmaf(zi[8],  q2.x, n0); n1 = fmaf(zi[9],  q2.y, n1);
            n2 = fmaf(zi[10], q2.z, n2); n3 = fmaf(zi[11], q2.w, n3);
            n0 = fmaf(zi[12], q3.x, n0); n1 = fmaf(zi[13], q3.y, n1);
            n2 = fmaf(zi[14], q3.z, n2); n3 = fmaf(zi[15], q3.w, n3);
            float nr = (bi + bt[j]) - ((n0 + n1) + (n2 + n3));
            nr = fmaxf(nr, nclamp);
            float p = __builtin_amdgcn_exp2f(nr);
            float P = __builtin_amdgcn_rcpf(1.0f + p);
            rs += P;
            const float4* xr = reinterpret_cast<const float4*>(&xt[j][0]);
            #pragma unroll
            for (int c = 0; c < 15; ++c) {
                float4 xv = xr[c];
                acc[c*4+0] = fmaf(P, xv.x, acc[c*4+0]);
                acc[c*4+1] = fmaf(P, xv.y, acc[c*4+1]);
                acc[c*4+2] = fmaf(P, xv.z, acc[c*4+2]);
                acc[c*4+3] = fmaf(P, xv.w, acc[c*4+3]);
            }
        }
        __syncthreads();
    }

    float* dst = hacc + (size_t)i * 61;
    #pragma unroll
    for (int k = 0; k < DIN; ++k) unsafeAtomicAdd(dst + k, acc[k]);
    unsafeAtomicAdd(dst + 60, rs);
}

// ---------------------------------------------------------------------------
// K3: diagonal correction + normalize + fc3 + fc6 + softmax
// ---------------------------------------------------------------------------
__global__ __launch_bounds__(256) void k3_head(
    const float* __restrict__ x,
    const float* __restrict__ w3, const float* __restrict__ b3,
    const float* __restrict__ w6, const float* __restrict__ b6,
    const float* __restrict__ theta_p,
    const float* __restrict__ hacc,
    float* __restrict__ out)
{
    int i = blockIdx.x * 256 + threadIdx.x;
    float theta = *theta_p;
    float sig  = __builtin_amdgcn_rcpf(1.0f + __builtin_amdgcn_exp2f(-theta * LOG2E));
    float corr = 1.0f - sig;   // replace diagonal sigma(theta) with 1

    const float* hi = hacc + (size_t)i * 61;
    const float* xi = x + (size_t)i * DIN;

    float denom = hi[60] + corr;
    float rd = __builtin_amdgcn_rcpf(denom);

    float h[DIN];
    #pragma unroll
    for (int k = 0; k < DIN; ++k) h[k] = fmaf(corr, xi[k], hi[k]) * rd;

    float g[8];
    #pragma unroll
    for (int o = 0; o < 8; ++o) {
        float a = b3[o];
        #pragma unroll
        for (int k = 0; k < DIN; ++k) a = fmaf(w3[o*DIN+k], h[k], a);
        g[o] = a;
    }

    float l[NC];
    float m = -3.0e38f;
    #pragma unroll
    for (int c = 0; c < NC; ++c) {
        float a = b6[c];
        #pragma unroll
        for (int o = 0; o < 8; ++o) a = fmaf(w6[c*8+o], g[o], a);
        l[c] = a;
        m = fmaxf(m, a);
    }
    float e[NC];
    float sum = 0.0f;
    #pragma unroll
    for (int c = 0; c < NC; ++c) {
        e[c] = __builtin_amdgcn_exp2f((l[c] - m) * LOG2E);
        sum += e[c];
    }
    float rsum = __builtin_amdgcn_rcpf(sum);
    #pragma unroll
    for (int c = 0; c < NC; ++c) out[(size_t)i * NC + c] = e[c] * rsum;
}

// ---------------------------------------------------------------------------
extern "C" void kernel_launch(void* const* d_in, const int* in_sizes, int n_in,
                              void* d_out, int out_size, void* d_ws, size_t ws_size,
                              hipStream_t stream)
{
    const float* x     = (const float*)d_in[0];
    const float* w1    = (const float*)d_in[1];
    const float* b1    = (const float*)d_in[2];
    const float* w2    = (const float*)d_in[3];
    const float* b2    = (const float*)d_in[4];
    const float* w3    = (const float*)d_in[5];
    const float* b3    = (const float*)d_in[6];
    const float* w6    = (const float*)d_in[7];
    const float* b6    = (const float*)d_in[8];
    const float* temp  = (const float*)d_in[9];
    const float* theta = (const float*)d_in[10];
    float* out = (float*)d_out;

    float* zp   = (float*)d_ws;          // [8192][16]
    float* bb   = zp + NROWS * DZ;       // [8192]
    float* hacc = bb + NROWS;            // [8192][61]

    hipMemsetAsync(hacc, 0, (size_t)NROWS * 61 * sizeof(float), stream);
    k1_embed<<<NROWS / 256, 256, 0, stream>>>(x, w1, b1, w2, b2, temp, theta, zp, bb);
    k2_pair<<<NRB * NCH, 256, 0, stream>>>(x, zp, bb, theta, hacc);
    k3_head<<<NROWS / 256, 256, 0, stream>>>(x, w3, b3, w6, b6, theta, hacc, out);
}

// Round 2
// 347.855 us; speedup vs baseline: 3.2370x; 3.2370x over previous
//
#include <hip/hip_runtime.h>
#include <math.h>

#define NROWS 8192
#define DIN   60
#define DZ    16
#define NC    10

#define LOG2E 1.4426950408889634f

// K2 tiling
#define RB  256               // rows per block (1 per thread)
#define CJ  256               // j-range per block (chunk)
#define NRB (NROWS / RB)      // 32 row blocks
#define NCH (NROWS / CJ)      // 32 j chunks

// ---------------------------------------------------------------------------
// K1: z = fc2(fc1(x)); store z' = z * sqrt(2*temp*log2e) and
//     b_i = log2e*(temp*||z||^2 - theta/2)
// ---------------------------------------------------------------------------
__global__ __launch_bounds__(256) void k1_embed(
    const float* __restrict__ x,
    const float* __restrict__ w1, const float* __restrict__ b1,
    const float* __restrict__ w2, const float* __restrict__ b2,
    const float* __restrict__ temp_p, const float* __restrict__ theta_p,
    float* __restrict__ zp, float* __restrict__ bb)
{
    int i = blockIdx.x * 256 + threadIdx.x;

    float xr[DIN];
    const float4* xp = reinterpret_cast<const float4*>(x + i * DIN);
    #pragma unroll
    for (int c = 0; c < 15; ++c) {
        float4 v = xp[c];
        xr[c*4+0] = v.x; xr[c*4+1] = v.y; xr[c*4+2] = v.z; xr[c*4+3] = v.w;
    }

    float n1[32];
    #pragma unroll
    for (int o = 0; o < 32; ++o) {
        float acc = b1[o];
        #pragma unroll
        for (int k = 0; k < DIN; ++k) acc = fmaf(w1[o*DIN+k], xr[k], acc);
        n1[o] = acc;
    }

    float z[DZ];
    float sq = 0.0f;
    #pragma unroll
    for (int u = 0; u < DZ; ++u) {
        float acc = b2[u];
        #pragma unroll
        for (int o = 0; o < 32; ++o) acc = fmaf(w2[u*32+o], n1[o], acc);
        z[u] = acc;
        sq = fmaf(acc, acc, sq);
    }

    float temp  = *temp_p;
    float theta = *theta_p;
    float s = sqrtf(2.0f * temp * LOG2E);
    #pragma unroll
    for (int u = 0; u < DZ; ++u) zp[i*DZ + u] = z[u] * s;
    bb[i] = LOG2E * fmaf(temp, sq, -0.5f * theta);
}

// ---------------------------------------------------------------------------
// K2: fused pairwise sigmoid + aggregation. No LDS: x_j / z'_j / b_j have
// wave-uniform addresses -> s_load into SGPRs (K$ broadcast), acc stays in
// VGPRs. TWOSTAGE=1 writes per-chunk partials to ws; =0 uses global atomics.
//   P_ij = 1/(1+exp2(max(b_i + b_j - z'_i.z'_j, -theta*log2e)))
// ---------------------------------------------------------------------------
template<int TWOSTAGE>
__global__ __launch_bounds__(256, 4) void k2_pair(
    const float* __restrict__ x,
    const float* __restrict__ zp, const float* __restrict__ bb,
    const float* __restrict__ theta_p,
    float* __restrict__ hacc)   // TWOSTAGE: [NCH][NROWS][64], else [NROWS][61]
{
    const int tid = threadIdx.x;
    const int rb  = blockIdx.x & (NRB - 1);
    const int ch  = blockIdx.x >> 5;          // NRB == 32
    const int i   = rb * RB + tid;
    const int j0  = ch * CJ;

    float zi[DZ];
    const float4* zpi = reinterpret_cast<const float4*>(zp + (size_t)i * DZ);
    #pragma unroll
    for (int c = 0; c < 4; ++c) {
        float4 v = zpi[c];
        zi[c*4+0] = v.x; zi[c*4+1] = v.y; zi[c*4+2] = v.z; zi[c*4+3] = v.w;
    }
    const float bi = bb[i];
    const float nclamp = -(*theta_p) * LOG2E;

    float acc[DIN];
    #pragma unroll
    for (int k = 0; k < DIN; ++k) acc[k] = 0.0f;
    float rs = 0.0f;

    for (int j = j0; j < j0 + CJ; j += 2) {
        // ---- uniform-address loads (expected s_load -> SGPR broadcast) ----
        const float4* zj0 = reinterpret_cast<const float4*>(zp + (size_t)j * DZ);
        const float4* zj1 = reinterpret_cast<const float4*>(zp + (size_t)(j + 1) * DZ);
        float4 a0 = zj0[0], a1 = zj0[1], a2 = zj0[2], a3 = zj0[3];
        float4 c0 = zj1[0], c1 = zj1[1], c2 = zj1[2], c3 = zj1[3];
        float bj0 = bb[j], bj1 = bb[j + 1];

        float d0 = zi[0] * a0.x, d1 = zi[1] * a0.y, d2 = zi[2] * a0.z, d3 = zi[3] * a0.w;
        float e0 = zi[0] * c0.x, e1 = zi[1] * c0.y, e2 = zi[2] * c0.z, e3 = zi[3] * c0.w;
        d0 = fmaf(zi[4],  a1.x, d0); d1 = fmaf(zi[5],  a1.y, d1);
        d2 = fmaf(zi[6],  a1.z, d2); d3 = fmaf(zi[7],  a1.w, d3);
        e0 = fmaf(zi[4],  c1.x, e0); e1 = fmaf(zi[5],  c1.y, e1);
        e2 = fmaf(zi[6],  c1.z, e2); e3 = fmaf(zi[7],  c1.w, e3);
        d0 = fmaf(zi[8],  a2.x, d0); d1 = fmaf(zi[9],  a2.y, d1);
        d2 = fmaf(zi[10], a2.z, d2); d3 = fmaf(zi[11], a2.w, d3);
        e0 = fmaf(zi[8],  c2.x, e0); e1 = fmaf(zi[9],  c2.y, e1);
        e2 = fmaf(zi[10], c2.z, e2); e3 = fmaf(zi[11], c2.w, e3);
        d0 = fmaf(zi[12], a3.x, d0); d1 = fmaf(zi[13], a3.y, d1);
        d2 = fmaf(zi[14], a3.z, d2); d3 = fmaf(zi[15], a3.w, d3);
        e0 = fmaf(zi[12], c3.x, e0); e1 = fmaf(zi[13], c3.y, e1);
        e2 = fmaf(zi[14], c3.z, e2); e3 = fmaf(zi[15], c3.w, e3);

        float n0 = (bi + bj0) - ((d0 + d1) + (d2 + d3));
        float n1 = (bi + bj1) - ((e0 + e1) + (e2 + e3));
        n0 = fmaxf(n0, nclamp);
        n1 = fmaxf(n1, nclamp);
        float P0 = __builtin_amdgcn_rcpf(1.0f + __builtin_amdgcn_exp2f(n0));
        float P1 = __builtin_amdgcn_rcpf(1.0f + __builtin_amdgcn_exp2f(n1));
        rs += P0 + P1;

        const float4* x0 = reinterpret_cast<const float4*>(x + (size_t)j * DIN);
        const float4* x1 = reinterpret_cast<const float4*>(x + (size_t)(j + 1) * DIN);
        #pragma unroll
        for (int c = 0; c < 15; ++c) {
            float4 v0 = x0[c];
            float4 v1 = x1[c];
            acc[c*4+0] = fmaf(P0, v0.x, acc[c*4+0]);
            acc[c*4+1] = fmaf(P0, v0.y, acc[c*4+1]);
            acc[c*4+2] = fmaf(P0, v0.z, acc[c*4+2]);
            acc[c*4+3] = fmaf(P0, v0.w, acc[c*4+3]);
            acc[c*4+0] = fmaf(P1, v1.x, acc[c*4+0]);
            acc[c*4+1] = fmaf(P1, v1.y, acc[c*4+1]);
            acc[c*4+2] = fmaf(P1, v1.z, acc[c*4+2]);
            acc[c*4+3] = fmaf(P1, v1.w, acc[c*4+3]);
        }
    }

    if (TWOSTAGE) {
        float4* d4 = reinterpret_cast<float4*>(hacc + ((size_t)ch * NROWS + i) * 64);
        #pragma unroll
        for (int c = 0; c < 15; ++c)
            d4[c] = make_float4(acc[c*4+0], acc[c*4+1], acc[c*4+2], acc[c*4+3]);
        d4[15] = make_float4(rs, 0.0f, 0.0f, 0.0f);
    } else {
        float* dst = hacc + (size_t)i * 61;
        #pragma unroll
        for (int k = 0; k < DIN; ++k) unsafeAtomicAdd(dst + k, acc[k]);
        unsafeAtomicAdd(dst + 60, rs);
    }
}

// ---------------------------------------------------------------------------
// K3: (reduce partials) + diagonal correction + normalize + fc3 + fc6 + softmax
// ---------------------------------------------------------------------------
template<int TWOSTAGE>
__global__ __launch_bounds__(256) void k3_head(
    const float* __restrict__ x,
    const float* __restrict__ w3, const float* __restrict__ b3,
    const float* __restrict__ w6, const float* __restrict__ b6,
    const float* __restrict__ theta_p,
    const float* __restrict__ hacc,
    float* __restrict__ out)
{
    int i = blockIdx.x * 256 + threadIdx.x;
    float theta = *theta_p;
    float sig  = __builtin_amdgcn_rcpf(1.0f + __builtin_amdgcn_exp2f(-theta * LOG2E));
    float corr = 1.0f - sig;   // replace diagonal sigma(theta) with 1

    float h[DIN];
    float denom;
    if (TWOSTAGE) {
        float a[64];
        #pragma unroll
        for (int k = 0; k < 64; ++k) a[k] = 0.0f;
        for (int ch = 0; ch < NCH; ++ch) {
            const float4* p4 = reinterpret_cast<const float4*>(
                hacc + ((size_t)ch * NROWS + i) * 64);
            #pragma unroll
            for (int c = 0; c < 16; ++c) {
                float4 v = p4[c];
                a[c*4+0] += v.x; a[c*4+1] += v.y; a[c*4+2] += v.z; a[c*4+3] += v.w;
            }
        }
        #pragma unroll
        for (int k = 0; k < DIN; ++k) h[k] = a[k];
        denom = a[60];
    } else {
        const float* hi = hacc + (size_t)i * 61;
        #pragma unroll
        for (int k = 0; k < DIN; ++k) h[k] = hi[k];
        denom = hi[60];
    }

    const float* xi = x + (size_t)i * DIN;
    float rd = __builtin_amdgcn_rcpf(denom + corr);
    #pragma unroll
    for (int k = 0; k < DIN; ++k) h[k] = fmaf(corr, xi[k], h[k]) * rd;

    float g[8];
    #pragma unroll
    for (int o = 0; o < 8; ++o) {
        float a = b3[o];
        #pragma unroll
        for (int k = 0; k < DIN; ++k) a = fmaf(w3[o*DIN+k], h[k], a);
        g[o] = a;
    }

    float l[NC];
    float m = -3.0e38f;
    #pragma unroll
    for (int c = 0; c < NC; ++c) {
        float a = b6[c];
        #pragma unroll
        for (int o = 0; o < 8; ++o) a = fmaf(w6[c*8+o], g[o], a);
        l[c] = a;
        m = fmaxf(m, a);
    }
    float e[NC];
    float sum = 0.0f;
    #pragma unroll
    for (int c = 0; c < NC; ++c) {
        e[c] = __builtin_amdgcn_exp2f((l[c] - m) * LOG2E);
        sum += e[c];
    }
    float rsum = __builtin_amdgcn_rcpf(sum);
    #pragma unroll
    for (int c = 0; c < NC; ++c) out[(size_t)i * NC + c] = e[c] * rsum;
}

// ---------------------------------------------------------------------------
extern "C" void kernel_launch(void* const* d_in, const int* in_sizes, int n_in,
                              void* d_out, int out_size, void* d_ws, size_t ws_size,
                              hipStream_t stream)
{
    const float* x     = (const float*)d_in[0];
    const float* w1    = (const float*)d_in[1];
    const float* b1    = (const float*)d_in[2];
    const float* w2    = (const float*)d_in[3];
    const float* b2    = (const float*)d_in[4];
    const float* w3    = (const float*)d_in[5];
    const float* b3    = (const float*)d_in[6];
    const float* w6    = (const float*)d_in[7];
    const float* b6    = (const float*)d_in[8];
    const float* temp  = (const float*)d_in[9];
    const float* theta = (const float*)d_in[10];
    float* out = (float*)d_out;

    float* zp   = (float*)d_ws;          // [8192][16]
    float* bb   = zp + NROWS * DZ;       // [8192]
    float* hbuf = bb + NROWS;            // partials or accum

    size_t need2 = ((size_t)NROWS * DZ + NROWS + (size_t)NCH * NROWS * 64) * sizeof(float);
    bool twostage = (ws_size >= need2);

    k1_embed<<<NROWS / 256, 256, 0, stream>>>(x, w1, b1, w2, b2, temp, theta, zp, bb);
    if (twostage) {
        k2_pair<1><<<NRB * NCH, 256, 0, stream>>>(x, zp, bb, theta, hbuf);
        k3_head<1><<<NROWS / 256, 256, 0, stream>>>(x, w3, b3, w6, b6, theta, hbuf, out);
    } else {
        hipMemsetAsync(hbuf, 0, (size_t)NROWS * 61 * sizeof(float), stream);
        k2_pair<0><<<NRB * NCH, 256, 0, stream>>>(x, zp, bb, theta, hbuf);
        k3_head<0><<<NROWS / 256, 256, 0, stream>>>(x, w3, b3, w6, b6, theta, hbuf, out);
    }
}

// Round 3
// 308.657 us; speedup vs baseline: 3.6481x; 1.1270x over previous
//
#include <hip/hip_runtime.h>
#include <math.h>

#define NROWS 8192
#define DIN   60
#define DZ    16
#define NC    10

#define LOG2E 1.4426950408889634f

// K2 tiling
#define RB  256               // rows per block (1 per thread)
#define CJ  256               // j-range per block (chunk)
#define NRB (NROWS / RB)      // 32 row blocks
#define NCH (NROWS / CJ)      // 32 j chunks

typedef float v2f __attribute__((ext_vector_type(2)));

// ---------------------------------------------------------------------------
// K1: z = fc2(fc1(x)); store z' = z * sqrt(2*temp*log2e) and
//     b_i = log2e*(temp*||z||^2 - theta/2)
// ---------------------------------------------------------------------------
__global__ __launch_bounds__(256) void k1_embed(
    const float* __restrict__ x,
    const float* __restrict__ w1, const float* __restrict__ b1,
    const float* __restrict__ w2, const float* __restrict__ b2,
    const float* __restrict__ temp_p, const float* __restrict__ theta_p,
    float* __restrict__ zp, float* __restrict__ bb)
{
    int i = blockIdx.x * 256 + threadIdx.x;

    float xr[DIN];
    const float4* xp = reinterpret_cast<const float4*>(x + i * DIN);
    #pragma unroll
    for (int c = 0; c < 15; ++c) {
        float4 v = xp[c];
        xr[c*4+0] = v.x; xr[c*4+1] = v.y; xr[c*4+2] = v.z; xr[c*4+3] = v.w;
    }

    float n1[32];
    #pragma unroll
    for (int o = 0; o < 32; ++o) {
        float acc = b1[o];
        #pragma unroll
        for (int k = 0; k < DIN; ++k) acc = fmaf(w1[o*DIN+k], xr[k], acc);
        n1[o] = acc;
    }

    float z[DZ];
    float sq = 0.0f;
    #pragma unroll
    for (int u = 0; u < DZ; ++u) {
        float acc = b2[u];
        #pragma unroll
        for (int o = 0; o < 32; ++o) acc = fmaf(w2[u*32+o], n1[o], acc);
        z[u] = acc;
        sq = fmaf(acc, acc, sq);
    }

    float temp  = *temp_p;
    float theta = *theta_p;
    float s = sqrtf(2.0f * temp * LOG2E);
    #pragma unroll
    for (int u = 0; u < DZ; ++u) zp[i*DZ + u] = z[u] * s;
    bb[i] = LOG2E * fmaf(temp, sq, -0.5f * theta);
}

// ---------------------------------------------------------------------------
// K2: fused pairwise sigmoid + aggregation, packed-fp32 inner loop.
//   x_j / z'_j / b_j have wave-uniform addresses -> s_load (K$ broadcast);
//   <2 x float> ops select v_pk_fma_f32 (gfx90a+ packed fp32, 2x rate).
//   P_ij = 1/(1+exp2(max(b_i + b_j - z'_i.z'_j, -theta*log2e)))
// ---------------------------------------------------------------------------
template<int TWOSTAGE>
__global__ __launch_bounds__(256, 4) void k2_pair(
    const float* __restrict__ x,
    const float* __restrict__ zp, const float* __restrict__ bb,
    const float* __restrict__ theta_p,
    float* __restrict__ hacc)   // TWOSTAGE: [NCH][NROWS][64], else [NROWS][61]
{
    const int tid = threadIdx.x;
    const int rb  = blockIdx.x & (NRB - 1);
    const int ch  = blockIdx.x >> 5;          // NRB == 32
    const int i   = rb * RB + tid;
    const int j0  = ch * CJ;

    v2f zi2[8];
    {
        const v2f* zpi = reinterpret_cast<const v2f*>(zp + (size_t)i * DZ);
        #pragma unroll
        for (int c = 0; c < 8; ++c) zi2[c] = zpi[c];
    }
    const float bi = bb[i];
    const float nclamp = -(*theta_p) * LOG2E;

    v2f acc2[30];
    #pragma unroll
    for (int c = 0; c < 30; ++c) acc2[c] = (v2f)(0.0f);
    float rs = 0.0f;

    #pragma unroll 2
    for (int j = j0; j < j0 + CJ; ++j) {
        // uniform-address loads -> SGPR broadcast through K$
        const v2f* zj = reinterpret_cast<const v2f*>(zp + (size_t)j * DZ);
        v2f d = zi2[0] * zj[0];
        #pragma unroll
        for (int c = 1; c < 8; ++c) d = __builtin_elementwise_fma(zi2[c], zj[c], d);
        float dot = d.x + d.y;

        float n = (bi + bb[j]) - dot;
        n = fmaxf(n, nclamp);
        float P = __builtin_amdgcn_rcpf(1.0f + __builtin_amdgcn_exp2f(n));
        rs += P;
        v2f P2 = {P, P};

        const v2f* xj = reinterpret_cast<const v2f*>(x + (size_t)j * DIN);
        #pragma unroll
        for (int c = 0; c < 30; ++c)
            acc2[c] = __builtin_elementwise_fma(P2, xj[c], acc2[c]);
    }

    if (TWOSTAGE) {
        v2f* d2 = reinterpret_cast<v2f*>(hacc + ((size_t)ch * NROWS + i) * 64);
        #pragma unroll
        for (int c = 0; c < 30; ++c) d2[c] = acc2[c];
        d2[30] = (v2f){rs, 0.0f};      // col 60 = rowsum, 61..63 zeroed
        d2[31] = (v2f)(0.0f);
    } else {
        const float* af = reinterpret_cast<const float*>(acc2);
        float* dst = hacc + (size_t)i * 61;
        #pragma unroll
        for (int k = 0; k < DIN; ++k) unsafeAtomicAdd(dst + k, af[k]);
        unsafeAtomicAdd(dst + 60, rs);
    }
}

// ---------------------------------------------------------------------------
// K3r: wide reduction of [NCH][NROWS][64] partials into chunk 0 (in place).
//   256 blocks x 256 threads; 8 threads cover one 64-float row -> coalesced.
//   Each (row, col8) owned by exactly one thread: in-place write is safe.
// ---------------------------------------------------------------------------
__global__ __launch_bounds__(256) void k3_reduce(float* __restrict__ hacc)
{
    const int tid = threadIdx.x;
    const int r   = blockIdx.x * 32 + (tid >> 3);
    const int c   = (tid & 7) * 8;

    float s[8];
    #pragma unroll
    for (int k = 0; k < 8; ++k) s[k] = 0.0f;

    for (int ch = 0; ch < NCH; ++ch) {
        const float4* p = reinterpret_cast<const float4*>(
            hacc + ((size_t)ch * NROWS + r) * 64 + c);
        float4 v0 = p[0], v1 = p[1];
        s[0] += v0.x; s[1] += v0.y; s[2] += v0.z; s[3] += v0.w;
        s[4] += v1.x; s[5] += v1.y; s[6] += v1.z; s[7] += v1.w;
    }

    float4* q = reinterpret_cast<float4*>(hacc + (size_t)r * 64 + c);
    q[0] = make_float4(s[0], s[1], s[2], s[3]);
    q[1] = make_float4(s[4], s[5], s[6], s[7]);
}

// ---------------------------------------------------------------------------
// K3h: diagonal correction + normalize + fc3 + fc6 + softmax
// ---------------------------------------------------------------------------
template<int TWOSTAGE>
__global__ __launch_bounds__(256) void k3_head(
    const float* __restrict__ x,
    const float* __restrict__ w3, const float* __restrict__ b3,
    const float* __restrict__ w6, const float* __restrict__ b6,
    const float* __restrict__ theta_p,
    const float* __restrict__ hacc,
    float* __restrict__ out)
{
    int i = blockIdx.x * 256 + threadIdx.x;
    float theta = *theta_p;
    float sig  = __builtin_amdgcn_rcpf(1.0f + __builtin_amdgcn_exp2f(-theta * LOG2E));
    float corr = 1.0f - sig;   // replace diagonal sigma(theta) with 1

    float h[DIN];
    float denom;
    if (TWOSTAGE) {
        const float* hi = hacc + (size_t)i * 64;
        #pragma unroll
        for (int k = 0; k < DIN; ++k) h[k] = hi[k];
        denom = hi[60];
    } else {
        const float* hi = hacc + (size_t)i * 61;
        #pragma unroll
        for (int k = 0; k < DIN; ++k) h[k] = hi[k];
        denom = hi[60];
    }

    const float* xi = x + (size_t)i * DIN;
    float rd = __builtin_amdgcn_rcpf(denom + corr);
    #pragma unroll
    for (int k = 0; k < DIN; ++k) h[k] = fmaf(corr, xi[k], h[k]) * rd;

    float g[8];
    #pragma unroll
    for (int o = 0; o < 8; ++o) {
        float a = b3[o];
        #pragma unroll
        for (int k = 0; k < DIN; ++k) a = fmaf(w3[o*DIN+k], h[k], a);
        g[o] = a;
    }

    float l[NC];
    float m = -3.0e38f;
    #pragma unroll
    for (int c = 0; c < NC; ++c) {
        float a = b6[c];
        #pragma unroll
        for (int o = 0; o < 8; ++o) a = fmaf(w6[c*8+o], g[o], a);
        l[c] = a;
        m = fmaxf(m, a);
    }
    float e[NC];
    float sum = 0.0f;
    #pragma unroll
    for (int c = 0; c < NC; ++c) {
        e[c] = __builtin_amdgcn_exp2f((l[c] - m) * LOG2E);
        sum += e[c];
    }
    float rsum = __builtin_amdgcn_rcpf(sum);
    #pragma unroll
    for (int c = 0; c < NC; ++c) out[(size_t)i * NC + c] = e[c] * rsum;
}

// ---------------------------------------------------------------------------
extern "C" void kernel_launch(void* const* d_in, const int* in_sizes, int n_in,
                              void* d_out, int out_size, void* d_ws, size_t ws_size,
                              hipStream_t stream)
{
    const float* x     = (const float*)d_in[0];
    const float* w1    = (const float*)d_in[1];
    const float* b1    = (const float*)d_in[2];
    const float* w2    = (const float*)d_in[3];
    const float* b2    = (const float*)d_in[4];
    const float* w3    = (const float*)d_in[5];
    const float* b3    = (const float*)d_in[6];
    const float* w6    = (const float*)d_in[7];
    const float* b6    = (const float*)d_in[8];
    const float* temp  = (const float*)d_in[9];
    const float* theta = (const float*)d_in[10];
    float* out = (float*)d_out;

    float* zp   = (float*)d_ws;          // [8192][16]
    float* bb   = zp + NROWS * DZ;       // [8192]
    float* hbuf = bb + NROWS;            // partials or accum

    size_t need2 = ((size_t)NROWS * DZ + NROWS + (size_t)NCH * NROWS * 64) * sizeof(float);
    bool twostage = (ws_size >= need2);

    k1_embed<<<NROWS / 256, 256, 0, stream>>>(x, w1, b1, w2, b2, temp, theta, zp, bb);
    if (twostage) {
        k2_pair<1><<<NRB * NCH, 256, 0, stream>>>(x, zp, bb, theta, hbuf);
        k3_reduce<<<NROWS / 32, 256, 0, stream>>>(hbuf);
        k3_head<1><<<NROWS / 256, 256, 0, stream>>>(x, w3, b3, w6, b6, theta, hbuf, out);
    } else {
        hipMemsetAsync(hbuf, 0, (size_t)NROWS * 61 * sizeof(float), stream);
        k2_pair<0><<<NRB * NCH, 256, 0, stream>>>(x, zp, bb, theta, hbuf);
        k3_head<0><<<NROWS / 256, 256, 0, stream>>>(x, w3, b3, w6, b6, theta, hbuf, out);
    }
}

// Round 4
// 180.966 us; speedup vs baseline: 6.2223x; 1.7056x over previous
//
#include <hip/hip_runtime.h>
#include <math.h>

#define NROWS 8192
#define DIN   60
#define DZ    16
#define NC    10

#define LOG2E 1.4426950408889634f

// K2 tiling: block = 512 thr (8 waves), 256 rows x 512 cols per block
#define RB  256
#define CJ  512
#define NRB (NROWS / RB)      // 32 row blocks
#define NCH (NROWS / CJ)      // 16 col chunks

typedef short bf16x8 __attribute__((ext_vector_type(8)));
typedef float f32x4  __attribute__((ext_vector_type(4)));

__device__ __forceinline__ unsigned int bfr(float f) {
    // bf16 bits, round-half-up (bias-free to 0.5 ulp)
    return (__float_as_uint(f) + 0x8000u) >> 16;
}

// ---------------------------------------------------------------------------
// K1: z = fc2(fc1(x)); store zb = bf16(z * sqrt(2*temp*log2e)) padded with
//     zeros to 32 K-slots, and bbf_i = log2e*(temp*||z||^2 - theta/2)
// ---------------------------------------------------------------------------
__global__ __launch_bounds__(256) void k1_embed(
    const float* __restrict__ x,
    const float* __restrict__ w1, const float* __restrict__ b1,
    const float* __restrict__ w2, const float* __restrict__ b2,
    const float* __restrict__ temp_p, const float* __restrict__ theta_p,
    unsigned short* __restrict__ zb, float* __restrict__ bbf)
{
    int i = blockIdx.x * 256 + threadIdx.x;

    float xr[DIN];
    const float4* xp = reinterpret_cast<const float4*>(x + (size_t)i * DIN);
    #pragma unroll
    for (int c = 0; c < 15; ++c) {
        float4 v = xp[c];
        xr[c*4+0] = v.x; xr[c*4+1] = v.y; xr[c*4+2] = v.z; xr[c*4+3] = v.w;
    }

    float n1[32];
    #pragma unroll
    for (int o = 0; o < 32; ++o) {
        float acc = b1[o];
        #pragma unroll
        for (int k = 0; k < DIN; ++k) acc = fmaf(w1[o*DIN+k], xr[k], acc);
        n1[o] = acc;
    }

    float z[DZ];
    float sq = 0.0f;
    #pragma unroll
    for (int u = 0; u < DZ; ++u) {
        float acc = b2[u];
        #pragma unroll
        for (int o = 0; o < 32; ++o) acc = fmaf(w2[u*32+o], n1[o], acc);
        z[u] = acc;
        sq = fmaf(acc, acc, sq);
    }

    float temp  = *temp_p;
    float theta = *theta_p;
    float s = sqrtf(2.0f * temp * LOG2E);

    unsigned int p[8];
    #pragma unroll
    for (int u = 0; u < 8; ++u) {
        unsigned int lo = bfr(z[2*u]   * s);
        unsigned int hi = bfr(z[2*u+1] * s);
        p[u] = lo | (hi << 16);
    }
    uint4* dst = reinterpret_cast<uint4*>(zb + (size_t)i * 32);
    dst[0] = make_uint4(p[0], p[1], p[2], p[3]);
    dst[1] = make_uint4(p[4], p[5], p[6], p[7]);
    dst[2] = make_uint4(0, 0, 0, 0);     // zero K-slots 16..31
    dst[3] = make_uint4(0, 0, 0, 0);

    bbf[i] = LOG2E * fmaf(temp, sq, -0.5f * theta);
}

// ---------------------------------------------------------------------------
// K1x: xT[n][i] = bf16(x[i][n]) for n<60; row 60 = 1.0 (rowsum column),
//      rows 61..63 = 0. Stores are lane-contiguous (coalesced).
// ---------------------------------------------------------------------------
__global__ __launch_bounds__(256) void k1_xt(
    const float* __restrict__ x, unsigned short* __restrict__ xT)
{
    int i = blockIdx.x * 256 + threadIdx.x;
    float xr[DIN];
    const float4* xp = reinterpret_cast<const float4*>(x + (size_t)i * DIN);
    #pragma unroll
    for (int c = 0; c < 15; ++c) {
        float4 v = xp[c];
        xr[c*4+0] = v.x; xr[c*4+1] = v.y; xr[c*4+2] = v.z; xr[c*4+3] = v.w;
    }
    #pragma unroll
    for (int c = 0; c < DIN; ++c)
        xT[(size_t)c * NROWS + i] = (unsigned short)bfr(xr[c]);
    xT[(size_t)60 * NROWS + i] = 0x3F80;  // 1.0
    xT[(size_t)61 * NROWS + i] = 0;
    xT[(size_t)62 * NROWS + i] = 0;
    xT[(size_t)63 * NROWS + i] = 0;
}

// ---------------------------------------------------------------------------
// K2: MFMA flash-style pairwise.
//   Per wave: 32 rows (2 i-tiles). Swapped QK^T: S' = mfma(A=z_j, B=z_i)
//   -> C layout col = i (lane&15), row = j (4*(lane>>4)+reg).
//   sigmoid -> bf16 -> wave-private LDS (pitch 80B, 2-way-free) -> A-frag
//   for PV: H[i][n] += P[i][j] @ xT-aug, K=32 per step. Rowsum = col 60.
//   Diagonal P_ii zeroed; k3 adds +x_i / +1 exactly in fp32.
// ---------------------------------------------------------------------------
__global__ __launch_bounds__(512, 4) void k2_mfma(
    const unsigned short* __restrict__ zb, const float* __restrict__ bbf,
    const unsigned short* __restrict__ xT, const float* __restrict__ theta_p,
    float* __restrict__ hacc)   // [NCH][NROWS][64]
{
    __shared__ unsigned long long sP[8 * 320];   // 8 waves * 2560 B

    const int tid  = threadIdx.x;
    const int lane = tid & 63, wave = tid >> 6;
    const int q = lane & 15, g = lane >> 4;
    const int rb = blockIdx.x & (NRB - 1);
    const int ch = blockIdx.x / NRB;
    const int i0 = rb * RB + wave * 32;
    const int j0 = ch * CJ;

    bf16x8 zbi[2];
    float  bi[2];
    #pragma unroll
    for (int t = 0; t < 2; ++t) {
        zbi[t] = *reinterpret_cast<const bf16x8*>(zb + (size_t)(i0 + t*16 + q) * 32 + g*8);
        bi[t]  = bbf[i0 + t*16 + q];
    }
    const float nclamp = -(*theta_p) * LOG2E;
    const f32x4 z4 = {0.0f, 0.0f, 0.0f, 0.0f};

    f32x4 H[2][4];
    #pragma unroll
    for (int t = 0; t < 2; ++t)
        #pragma unroll
        for (int nt = 0; nt < 4; ++nt) H[t][nt] = z4;

    char* myP = reinterpret_cast<char*>(sP) + wave * 2560;

    for (int jp = 0; jp < CJ / 32; ++jp) {
        #pragma unroll
        for (int half = 0; half < 2; ++half) {
            const int gj = j0 + jp*32 + half*16;
            bf16x8 za = *reinterpret_cast<const bf16x8*>(zb + (size_t)(gj + q) * 32 + g*8);
            f32x4  bj = *reinterpret_cast<const f32x4*>(bbf + gj + 4*g);
            #pragma unroll
            for (int t = 0; t < 2; ++t) {
                f32x4 S = __builtin_amdgcn_mfma_f32_16x16x32_bf16(za, zbi[t], z4, 0, 0, 0);
                unsigned int ur[4];
                #pragma unroll
                for (int r = 0; r < 4; ++r) {
                    float n = (bi[t] + bj[r]) - S[r];
                    n = fmaxf(n, nclamp);
                    float P = __builtin_amdgcn_rcpf(1.0f + __builtin_amdgcn_exp2f(n));
                    if (i0 + t*16 == gj && q == 4*g + r) P = 0.0f;  // diag
                    ur[r] = __float_as_uint(P) + 0x8000u;
                }
                unsigned int pk0 = (ur[0] >> 16) | (ur[1] & 0xFFFF0000u);
                unsigned int pk1 = (ur[2] >> 16) | (ur[3] & 0xFFFF0000u);
                *reinterpret_cast<unsigned long long*>(
                    myP + t*1280 + q*80 + half*32 + g*8) =
                    ((unsigned long long)pk1 << 32) | pk0;
            }
        }
        // PV over this 32-j block
        const int jb = j0 + jp*32;
        bf16x8 pa[2];
        #pragma unroll
        for (int t = 0; t < 2; ++t)
            pa[t] = *reinterpret_cast<const bf16x8*>(myP + t*1280 + q*80 + g*16);
        #pragma unroll
        for (int nt = 0; nt < 4; ++nt) {
            bf16x8 xb = *reinterpret_cast<const bf16x8*>(
                xT + (size_t)(nt*16 + q) * NROWS + jb + g*8);
            H[0][nt] = __builtin_amdgcn_mfma_f32_16x16x32_bf16(pa[0], xb, H[0][nt], 0, 0, 0);
            H[1][nt] = __builtin_amdgcn_mfma_f32_16x16x32_bf16(pa[1], xb, H[1][nt], 0, 0, 0);
        }
    }

    // epilogue: C layout row = 4g+r (i within tile), col = q (n within tile)
    #pragma unroll
    for (int t = 0; t < 2; ++t)
        #pragma unroll
        for (int nt = 0; nt < 4; ++nt)
            #pragma unroll
            for (int r = 0; r < 4; ++r) {
                int row = i0 + t*16 + 4*g + r;
                hacc[((size_t)ch * NROWS + row) * 64 + nt*16 + q] = H[t][nt][r];
            }
}

// ---------------------------------------------------------------------------
// K3r: reduce [NCH][NROWS][64] partials into chunk 0 (in place).
// ---------------------------------------------------------------------------
__global__ __launch_bounds__(256) void k3_reduce(float* __restrict__ hacc)
{
    const int tid = threadIdx.x;
    const int r   = blockIdx.x * 32 + (tid >> 3);
    const int c   = (tid & 7) * 8;

    float s[8];
    #pragma unroll
    for (int k = 0; k < 8; ++k) s[k] = 0.0f;

    for (int ch = 0; ch < NCH; ++ch) {
        const float4* p = reinterpret_cast<const float4*>(
            hacc + ((size_t)ch * NROWS + r) * 64 + c);
        float4 v0 = p[0], v1 = p[1];
        s[0] += v0.x; s[1] += v0.y; s[2] += v0.z; s[3] += v0.w;
        s[4] += v1.x; s[5] += v1.y; s[6] += v1.z; s[7] += v1.w;
    }

    float4* q = reinterpret_cast<float4*>(hacc + (size_t)r * 64 + c);
    q[0] = make_float4(s[0], s[1], s[2], s[3]);
    q[1] = make_float4(s[4], s[5], s[6], s[7]);
}

// ---------------------------------------------------------------------------
// K3h: +x_i / +1 (exact diagonal), normalize, fc3, fc6, softmax
// ---------------------------------------------------------------------------
__global__ __launch_bounds__(256) void k3_head(
    const float* __restrict__ x,
    const float* __restrict__ w3, const float* __restrict__ b3,
    const float* __restrict__ w6, const float* __restrict__ b6,
    const float* __restrict__ hacc,
    float* __restrict__ out)
{
    int i = blockIdx.x * 256 + threadIdx.x;

    const float* hi = hacc + (size_t)i * 64;
    const float* xi = x + (size_t)i * DIN;

    float rd = __builtin_amdgcn_rcpf(hi[60] + 1.0f);

    float h[DIN];
    #pragma unroll
    for (int k = 0; k < DIN; ++k) h[k] = (hi[k] + xi[k]) * rd;

    float g[8];
    #pragma unroll
    for (int o = 0; o < 8; ++o) {
        float a = b3[o];
        #pragma unroll
        for (int k = 0; k < DIN; ++k) a = fmaf(w3[o*DIN+k], h[k], a);
        g[o] = a;
    }

    float l[NC];
    float m = -3.0e38f;
    #pragma unroll
    for (int c = 0; c < NC; ++c) {
        float a = b6[c];
        #pragma unroll
        for (int o = 0; o < 8; ++o) a = fmaf(w6[c*8+o], g[o], a);
        l[c] = a;
        m = fmaxf(m, a);
    }
    float e[NC];
    float sum = 0.0f;
    #pragma unroll
    for (int c = 0; c < NC; ++c) {
        e[c] = __builtin_amdgcn_exp2f((l[c] - m) * LOG2E);
        sum += e[c];
    }
    float rsum = __builtin_amdgcn_rcpf(sum);
    #pragma unroll
    for (int c = 0; c < NC; ++c) out[(size_t)i * NC + c] = e[c] * rsum;
}

// ---------------------------------------------------------------------------
extern "C" void kernel_launch(void* const* d_in, const int* in_sizes, int n_in,
                              void* d_out, int out_size, void* d_ws, size_t ws_size,
                              hipStream_t stream)
{
    const float* x     = (const float*)d_in[0];
    const float* w1    = (const float*)d_in[1];
    const float* b1    = (const float*)d_in[2];
    const float* w2    = (const float*)d_in[3];
    const float* b2    = (const float*)d_in[4];
    const float* w3    = (const float*)d_in[5];
    const float* b3    = (const float*)d_in[6];
    const float* w6    = (const float*)d_in[7];
    const float* b6    = (const float*)d_in[8];
    const float* temp  = (const float*)d_in[9];
    const float* theta = (const float*)d_in[10];
    float* out = (float*)d_out;

    // ws carve-up (33.6 MB total; rounds 2-3 proved ws >= 66 MB)
    char* p = (char*)d_ws;
    unsigned short* zbuf = (unsigned short*)p;  p += (size_t)NROWS * 32 * 2;   // 512 KB
    float*          bbf  = (float*)p;           p += (size_t)NROWS * 4;        // 32 KB
    unsigned short* xT   = (unsigned short*)p;  p += (size_t)64 * NROWS * 2;   // 1 MB
    float*          hbuf = (float*)p;           // [NCH][NROWS][64] = 32 MB

    k1_embed<<<NROWS / 256, 256, 0, stream>>>(x, w1, b1, w2, b2, temp, theta, zbuf, bbf);
    k1_xt   <<<NROWS / 256, 256, 0, stream>>>(x, xT);
    k2_mfma <<<NRB * NCH, 512, 0, stream>>>(zbuf, bbf, xT, theta, hbuf);
    k3_reduce<<<NROWS / 32, 256, 0, stream>>>(hbuf);
    k3_head <<<NROWS / 256, 256, 0, stream>>>(x, w3, b3, w6, b6, hbuf, out);
}